// Round 3
// baseline (153.688 us; speedup 1.0000x reference)
//
#include <hip/hip_runtime.h>
#include <math.h>

// Problem constants: B=256, T=1024, F=64, Z=32, H=512
#define NB 256
#define NT 1024
#define NF 64
#define NZ 32
#define NH 512
#define K1 96   // F + Z

// Algebraic reduction (carried from round 0): reference returns h2 after the
// FIRST scan step (time index T-1) with zero initial h/c:
//   - W_hh1/W_hh2 and the f-gate are dead
//   - c = sigmoid(i)*tanh(g); h = sigmoid(o)*tanh(c)
//   - out[b] = sum_j h2[b,j]*W_lin[j] + b_lin[0]
//
// Round-1 lesson (measured): grid.sync() over 1024 blocks ~50 us -> keep two
// stream-ordered kernels.
// Round-2 analysis: k_lstm2 was L3-BW-bound re-reading h1p 256x (128 MB at
// ~9 TB/s ~ 14 us). This round: 8 units/block (traffic 128->32 MB), and k1
// stages xin once per 8 units.
//
// h1p layout (workspace): [128][256] float4 — h1[j][b] packed 4-consecutive-j
// per lane: float index (j>>2)*(NB*4) + bt*4 + (j&3).

__device__ __forceinline__ float sigmoidf_(float x) {
    return 1.0f / (1.0f + __expf(-x));
}

// ---------------------------------------------------------------------------
// layer 1 (with fused input staging): h1 = lstm_cell(xin) with h=c=0.
// grid 256 x 256 (4 waves/block): btb = blockIdx>>6 (batch quarter),
// g = blockIdx&63 (8 units/block). Wave wv handles units j0 = 8g + 2wv,
// full K=96. xin staged once per block into LDS.
// ---------------------------------------------------------------------------
__global__ __launch_bounds__(256) void k_lstm1f(
    const float* __restrict__ input, const float* __restrict__ z,
    const float* __restrict__ W_ih1, const float* __restrict__ b_ih1,
    const float* __restrict__ b_hh1, const float* __restrict__ b_lin,
    float* __restrict__ h1p, float* __restrict__ out)
{
    const int tid  = threadIdx.x;
    const int lane = tid & 63;
    const int wv   = __builtin_amdgcn_readfirstlane(tid >> 6); // 0..3
    const int btb  = blockIdx.x >> 6;      // 0..3
    const int g    = blockIdx.x & 63;      // 8-unit group
    const int bt   = btb * 64 + lane;
    const int j0   = 8 * g + 2 * wv;       // this wave's 2 units

    __shared__ float4 xin[24][64];         // 24 KB: xin[k4][local_batch]

    // ---- stage xin for this block's 64 batches (256 threads cooperate) -----
    {
        const int lb  = tid >> 2;          // local batch 0..63
        const int q   = tid & 3;
        const int gbt = btb * 64 + lb;
        const float4* __restrict__ in4 =
            (const float4*)input + (size_t)gbt * (NT * NF / 4) + ((NT - 1) * NF / 4);
        const float4* __restrict__ z4 =
            (const float4*)z + (size_t)gbt * (NZ / 4);
        #pragma unroll
        for (int i = 0; i < 4; ++i) {
            int k4 = q + i * 4;            // 0..15
            xin[k4][lb] = in4[k4];
        }
        #pragma unroll
        for (int i = 0; i < 2; ++i) {
            int k4 = q + i * 4;            // 0..7
            xin[16 + k4][lb] = z4[k4];
        }
        // out init (one g per batch quarter); k_lstm2's atomics are ordered
        // after this by stream-serialized dispatch.
        if (g == 0 && tid < 64) out[btb * 64 + tid] = b_lin[0];
    }
    __syncthreads();

    // ---- layer-1 cell: 2 units, 6 weight rows, K=96 ------------------------
    const float* __restrict__ w[6];
    #pragma unroll
    for (int u = 0; u < 2; ++u) {
        w[u * 3 + 0] = W_ih1 + (size_t)(j0 + u) * K1;          // i-gate
        w[u * 3 + 1] = W_ih1 + (size_t)(1024 + j0 + u) * K1;   // g-gate
        w[u * 3 + 2] = W_ih1 + (size_t)(1536 + j0 + u) * K1;   // o-gate
    }

    float acc[6] = {0, 0, 0, 0, 0, 0};
    #pragma unroll
    for (int k4 = 0; k4 < 24; ++k4) {
        float4 h = xin[k4][lane];          // ds_read_b128, conflict-free
        #pragma unroll
        for (int r = 0; r < 6; ++r) {
            const float* wr = w[r] + k4 * 4;   // wave-uniform -> s_load
            acc[r] = fmaf(wr[0], h.x, acc[r]);
            acc[r] = fmaf(wr[1], h.y, acc[r]);
            acc[r] = fmaf(wr[2], h.z, acc[r]);
            acc[r] = fmaf(wr[3], h.w, acc[r]);
        }
    }

    float hu[2];
    #pragma unroll
    for (int u = 0; u < 2; ++u) {
        int j = j0 + u;
        float gi = acc[u * 3 + 0] + b_ih1[j]        + b_hh1[j];
        float gg = acc[u * 3 + 1] + b_ih1[1024 + j] + b_hh1[1024 + j];
        float go = acc[u * 3 + 2] + b_ih1[1536 + j] + b_hh1[1536 + j];
        float c1 = sigmoidf_(gi) * tanhf(gg);
        hu[u] = sigmoidf_(go) * tanhf(c1);
    }
    // packed store: j0 even -> 8B-aligned float2
    *(float2*)(h1p + (j0 >> 2) * (NB * 4) + bt * 4 + (j0 & 3)) =
        make_float2(hu[0], hu[1]);
}

// ---------------------------------------------------------------------------
// layer 2 + linear: h2 = lstm_cell(h1); out[bt] += h2 . W_lin  (atomic).
// grid 256 x 512 (8 waves/block): btb = blockIdx>>6, g = blockIdx&63 covering
// 8 units (24 live weight rows). Wave wv takes K-chunk [wv*64, wv*64+64);
// partials reduced via LDS; wave 0 does the epilogue.
// h1p traffic: 256 blocks x 128 KB = 32 MB (was 128 MB with 2 units/block).
// ---------------------------------------------------------------------------
__global__ __launch_bounds__(512) void k_lstm2(
    const float* __restrict__ W_ih2, const float* __restrict__ b_ih2,
    const float* __restrict__ b_hh2, const float* __restrict__ W_lin,
    const float* __restrict__ h1p, float* __restrict__ out)
{
    const int tid  = threadIdx.x;
    const int lane = tid & 63;
    const int wv   = __builtin_amdgcn_readfirstlane(tid >> 6); // 0..7
    const int btb  = blockIdx.x >> 6;      // 0..3
    const int g    = blockIdx.x & 63;      // 8-unit group
    const int bt   = btb * 64 + lane;
    const int j0   = 8 * g;

    const float4* __restrict__ hv = (const float4*)h1p + bt;

    // 3 gate-base pointers; all row/k offsets are compile-time immediates
    // (u*NH*4 + k4i*16 <= 16 KB, within s_load's 21-bit signed offset).
    const float* __restrict__ pw0 = W_ih2 + (size_t)(j0) * NH;          // i
    const float* __restrict__ pw1 = W_ih2 + (size_t)(1024 + j0) * NH;   // g
    const float* __restrict__ pw2 = W_ih2 + (size_t)(1536 + j0) * NH;   // o

    float acc[3][8];
    #pragma unroll
    for (int gb = 0; gb < 3; ++gb)
        #pragma unroll
        for (int u = 0; u < 8; ++u) acc[gb][u] = 0.0f;

    const int k4base = wv * 16;            // 16 float4 iters = 64 K per wave
    #pragma unroll 4
    for (int k4i = 0; k4i < 16; ++k4i) {
        const int k4 = k4base + k4i;
        float4 h = hv[k4 * NB];            // coalesced 16B/lane, L3-resident
        const float* __restrict__ pb[3] = { pw0 + k4 * 4, pw1 + k4 * 4, pw2 + k4 * 4 };
        #pragma unroll
        for (int gb = 0; gb < 3; ++gb) {
            #pragma unroll
            for (int u = 0; u < 8; ++u) {
                const float* wr = pb[gb] + u * NH;   // wave-uniform -> s_load
                acc[gb][u] = fmaf(wr[0], h.x, acc[gb][u]);
                acc[gb][u] = fmaf(wr[1], h.y, acc[gb][u]);
                acc[gb][u] = fmaf(wr[2], h.z, acc[gb][u]);
                acc[gb][u] = fmaf(wr[3], h.w, acc[gb][u]);
            }
        }
    }

    __shared__ float red[8][24][64];       // 48 KB
    #pragma unroll
    for (int gb = 0; gb < 3; ++gb)
        #pragma unroll
        for (int u = 0; u < 8; ++u)
            red[wv][gb * 8 + u][lane] = acc[gb][u];
    __syncthreads();

    if (wv == 0) {
        float s[24];
        #pragma unroll
        for (int r = 0; r < 24; ++r) {
            float t = 0.0f;
            #pragma unroll
            for (int w8 = 0; w8 < 8; ++w8) t += red[w8][r][lane];
            s[r] = t;
        }
        float partial = 0.0f;
        #pragma unroll
        for (int u = 0; u < 8; ++u) {
            int j = j0 + u;
            float gi = s[0 * 8 + u] + b_ih2[j]        + b_hh2[j];
            float gg = s[1 * 8 + u] + b_ih2[1024 + j] + b_hh2[1024 + j];
            float go = s[2 * 8 + u] + b_ih2[1536 + j] + b_hh2[1536 + j];
            float c2 = sigmoidf_(gi) * tanhf(gg);
            float h2 = sigmoidf_(go) * tanhf(c2);
            partial  = fmaf(h2, W_lin[j], partial);
        }
        atomicAdd(out + bt, partial);
    }
}

// ---------------------------------------------------------------------------
extern "C" void kernel_launch(void* const* d_in, const int* in_sizes, int n_in,
                              void* d_out, int out_size, void* d_ws, size_t ws_size,
                              hipStream_t stream) {
    const float* input = (const float*)d_in[0];
    const float* z     = (const float*)d_in[1];
    // d_in[2]=h0, d_in[3]=c0 zeros -> unused; d_in[5]=W_hh1, d_in[9]=W_hh2 dead
    const float* W_ih1 = (const float*)d_in[4];
    const float* b_ih1 = (const float*)d_in[6];
    const float* b_hh1 = (const float*)d_in[7];
    const float* W_ih2 = (const float*)d_in[8];
    const float* b_ih2 = (const float*)d_in[10];
    const float* b_hh2 = (const float*)d_in[11];
    const float* W_lin = (const float*)d_in[12];
    const float* b_lin = (const float*)d_in[13];

    float* out = (float*)d_out;            // 256 floats
    float* h1p = (float*)d_ws;             // 128*256*4 floats (512 KB)

    k_lstm1f<<<256, 256, 0, stream>>>(input, z, W_ih1, b_ih1, b_hh1, b_lin,
                                      h1p, out);
    k_lstm2 <<<256, 512, 0, stream>>>(W_ih2, b_ih2, b_hh2, W_lin, h1p, out);
}

// Round 4
// 144.783 us; speedup vs baseline: 1.0615x; 1.0615x over previous
//
#include <hip/hip_runtime.h>
#include <math.h>

// Problem constants: B=256, T=1024, F=64, Z=32, H=512
#define NB 256
#define NT 1024
#define NF 64
#define NZ 32
#define NH 512
#define K1 96   // F + Z

// Algebraic reduction (carried from round 0): reference returns h2 after the
// FIRST scan step (time index T-1) with zero initial h/c:
//   - W_hh1/W_hh2 and the f-gate are dead
//   - c = sigmoid(i)*tanh(g); h = sigmoid(o)*tanh(c)
//   - out[b] = sum_j h2[b,j]*W_lin[j] + b_lin[0]
//
// Round-1 lesson: grid.sync() over 1024 blocks ~50 us -> two stream kernels.
// Round-3 lesson: U=8/block blew the SGPR budget (96 weight floats) and
// halved occupancy -> regressed. This round: U=4 at CONSTANT occupancy
// (512 blocks x 8 waves = 16 waves/CU), 12 rows/wave = 48 weight SGPRs.
// h1p re-read traffic 128 MB -> 64 MB; k_lstm1f byte-identical to round 2.
//
// h1p layout (workspace): [128][256] float4 — h1[j][b] packed 4-consecutive-j
// per lane: float index (j>>2)*(NB*4) + bt*4 + (j&3).

__device__ __forceinline__ float sigmoidf_(float x) {
    return 1.0f / (1.0f + __expf(-x));
}

// ---------------------------------------------------------------------------
// layer 1 (with fused input staging): h1 = lstm_cell(xin) with h=c=0.
// grid 1024 x 64 (1 wave/block): btb = blockIdx>>8, group g = blockIdx&255.
// Each wave: 2 hidden units (6 weight rows), K=96 as 24 float4 iters.
// (Byte-identical to the round-2 143.6 us version.)
// ---------------------------------------------------------------------------
__global__ __launch_bounds__(64) void k_lstm1f(
    const float* __restrict__ input, const float* __restrict__ z,
    const float* __restrict__ W_ih1, const float* __restrict__ b_ih1,
    const float* __restrict__ b_hh1, const float* __restrict__ b_lin,
    float* __restrict__ h1p, float* __restrict__ out)
{
    const int lane = threadIdx.x;
    const int btb  = blockIdx.x >> 8;      // 0..3
    const int g    = blockIdx.x & 255;     // unit-group (2 units)
    const int bt   = btb * 64 + lane;
    const int j0   = 2 * g;

    __shared__ float4 xin[24][64];         // 24 KB: xin[k4][local_batch]

    // ---- stage xin for this block's 64 batches (lane = own batch) ----------
    {
        const float4* __restrict__ in4 =
            (const float4*)input + (size_t)bt * (NT * NF / 4) + ((NT - 1) * NF / 4);
        const float4* __restrict__ z4 =
            (const float4*)z + (size_t)bt * (NZ / 4);
        #pragma unroll
        for (int k4 = 0; k4 < 16; ++k4) xin[k4][lane] = in4[k4];
        #pragma unroll
        for (int k4 = 0; k4 < 8; ++k4)  xin[16 + k4][lane] = z4[k4];
        if (g == 0) out[bt] = b_lin[0];
    }
    __syncthreads();

    // ---- layer-1 cell: 2 units, 6 weight rows, K=96 ------------------------
    const float* __restrict__ w[6];
    #pragma unroll
    for (int u = 0; u < 2; ++u) {
        w[u * 3 + 0] = W_ih1 + (size_t)(j0 + u) * K1;          // i-gate
        w[u * 3 + 1] = W_ih1 + (size_t)(1024 + j0 + u) * K1;   // g-gate
        w[u * 3 + 2] = W_ih1 + (size_t)(1536 + j0 + u) * K1;   // o-gate
    }

    float acc[6] = {0, 0, 0, 0, 0, 0};
    #pragma unroll
    for (int k4 = 0; k4 < 24; ++k4) {
        float4 h = xin[k4][lane];          // ds_read_b128, conflict-free
        #pragma unroll
        for (int r = 0; r < 6; ++r) {
            const float* wr = w[r] + k4 * 4;   // wave-uniform -> s_load
            acc[r] = fmaf(wr[0], h.x, acc[r]);
            acc[r] = fmaf(wr[1], h.y, acc[r]);
            acc[r] = fmaf(wr[2], h.z, acc[r]);
            acc[r] = fmaf(wr[3], h.w, acc[r]);
        }
    }

    float hu[2];
    #pragma unroll
    for (int u = 0; u < 2; ++u) {
        int j = j0 + u;
        float gi = acc[u * 3 + 0] + b_ih1[j]        + b_hh1[j];
        float gg = acc[u * 3 + 1] + b_ih1[1024 + j] + b_hh1[1024 + j];
        float go = acc[u * 3 + 2] + b_ih1[1536 + j] + b_hh1[1536 + j];
        float c1 = sigmoidf_(gi) * tanhf(gg);
        hu[u] = sigmoidf_(go) * tanhf(c1);
    }
    *(float2*)(h1p + (j0 >> 2) * (NB * 4) + bt * 4 + (j0 & 3)) =
        make_float2(hu[0], hu[1]);
}

// ---------------------------------------------------------------------------
// layer 2 + linear: h2 = lstm_cell(h1); out[bt] += h2 . W_lin  (atomic).
// grid 512 x 512 (8 waves/block, 2 blocks/CU, 16 waves/CU): btb =
// blockIdx>>7, g = blockIdx&127 covering 4 units (12 live weight rows,
// 48 weight SGPRs -> s_load path preserved). Wave wv takes K-chunk
// [wv*64, wv*64+64); partials reduced via LDS; wave 0 does the epilogue.
// Same-g replicas (x, x+128, x+256, x+384) congruent mod 8 -> same XCD.
// h1p traffic: 512 blocks x 128 KB = 64 MB (round-2 had 128 MB).
// ---------------------------------------------------------------------------
__global__ __launch_bounds__(512) void k_lstm2(
    const float* __restrict__ W_ih2, const float* __restrict__ b_ih2,
    const float* __restrict__ b_hh2, const float* __restrict__ W_lin,
    const float* __restrict__ h1p, float* __restrict__ out)
{
    const int tid  = threadIdx.x;
    const int lane = tid & 63;
    const int wv   = __builtin_amdgcn_readfirstlane(tid >> 6); // 0..7
    const int btb  = blockIdx.x >> 7;      // 0..3
    const int g    = blockIdx.x & 127;     // 4-unit group
    const int bt   = btb * 64 + lane;
    const int j0   = 4 * g;

    const float4* __restrict__ hv = (const float4*)h1p + bt;

    const float* __restrict__ w[12];
    #pragma unroll
    for (int u = 0; u < 4; ++u) {
        w[u * 3 + 0] = W_ih2 + (size_t)(j0 + u) * NH;          // i-gate
        w[u * 3 + 1] = W_ih2 + (size_t)(1024 + j0 + u) * NH;   // g-gate
        w[u * 3 + 2] = W_ih2 + (size_t)(1536 + j0 + u) * NH;   // o-gate
    }

    float acc[12];
    #pragma unroll
    for (int r = 0; r < 12; ++r) acc[r] = 0.0f;

    const int k4base = wv * 16;            // 16 float4 iters = 64 K per wave
    #pragma unroll 4
    for (int k4i = 0; k4i < 16; ++k4i) {
        const int k4 = k4base + k4i;
        float4 h = hv[k4 * NB];            // coalesced 16B/lane
        #pragma unroll
        for (int r = 0; r < 12; ++r) {
            const float* wr = w[r] + k4 * 4;   // wave-uniform -> s_load
            acc[r] = fmaf(wr[0], h.x, acc[r]);
            acc[r] = fmaf(wr[1], h.y, acc[r]);
            acc[r] = fmaf(wr[2], h.z, acc[r]);
            acc[r] = fmaf(wr[3], h.w, acc[r]);
        }
    }

    __shared__ float red[8][12][64];       // 24 KB -> 2 blocks/CU fits
    #pragma unroll
    for (int r = 0; r < 12; ++r) red[wv][r][lane] = acc[r];
    __syncthreads();

    if (wv == 0) {
        float s[12];
        #pragma unroll
        for (int r = 0; r < 12; ++r) {
            float t = 0.0f;
            #pragma unroll
            for (int w8 = 0; w8 < 8; ++w8) t += red[w8][r][lane];
            s[r] = t;
        }
        float partial = 0.0f;
        #pragma unroll
        for (int u = 0; u < 4; ++u) {
            int j = j0 + u;
            float gi = s[u * 3 + 0] + b_ih2[j]        + b_hh2[j];
            float gg = s[u * 3 + 1] + b_ih2[1024 + j] + b_hh2[1024 + j];
            float go = s[u * 3 + 2] + b_ih2[1536 + j] + b_hh2[1536 + j];
            float c2 = sigmoidf_(gi) * tanhf(gg);
            float h2 = sigmoidf_(go) * tanhf(c2);
            partial  = fmaf(h2, W_lin[j], partial);
        }
        atomicAdd(out + bt, partial);
    }
}

// ---------------------------------------------------------------------------
extern "C" void kernel_launch(void* const* d_in, const int* in_sizes, int n_in,
                              void* d_out, int out_size, void* d_ws, size_t ws_size,
                              hipStream_t stream) {
    const float* input = (const float*)d_in[0];
    const float* z     = (const float*)d_in[1];
    // d_in[2]=h0, d_in[3]=c0 zeros -> unused; d_in[5]=W_hh1, d_in[9]=W_hh2 dead
    const float* W_ih1 = (const float*)d_in[4];
    const float* b_ih1 = (const float*)d_in[6];
    const float* b_hh1 = (const float*)d_in[7];
    const float* W_ih2 = (const float*)d_in[8];
    const float* b_ih2 = (const float*)d_in[10];
    const float* b_hh2 = (const float*)d_in[11];
    const float* W_lin = (const float*)d_in[12];
    const float* b_lin = (const float*)d_in[13];

    float* out = (float*)d_out;            // 256 floats
    float* h1p = (float*)d_ws;             // 128*256*4 floats (512 KB)

    k_lstm1f<<<1024,  64, 0, stream>>>(input, z, W_ih1, b_ih1, b_hh1, b_lin,
                                       h1p, out);
    k_lstm2 <<< 512, 512, 0, stream>>>(W_ih2, b_ih2, b_hh2, W_lin, h1p, out);
}